// Round 14
// baseline (3630.067 us; speedup 1.0000x reference)
//
#include <hip/hip_runtime.h>

// mRNN: h_{t+1} = h + 0.1*(-h + relu(h) @ W_eff^T + tonic + ext) + 0.01*noise
// out[b,t] = readout over relu(h[500:600]) via out_w
//
// R14 = R13 (844us) + r-distribution split across pipes: LDS return-BW model
// says 8 waves x 13 ds_read_b128 = 104KB/step = ~1250cy is the binder.
// Waves 0-4 keep LDS reads (65KB); waves 5-7 read r windows from a global
// L2-resident mirror (39KB on the idle VMEM pipe) via relaxed agent-scope
// atomic loads (bypass L1 -> no staleness). Owners write r to BOTH LDS and
// the mirror (1 extra u32 store); vmcnt(0)+lgkm(0) before the barrier
// publishes it (prefetches are ~1300cy old by then -> drain is cheap).
// Everything else identical to R13 (2 rows/lane, 26 resident quads, shfl
// combines, readout-on-dot-path, 1-step-ahead prefetch, one barrier).

typedef _Float16 f16;
typedef _Float16 f16x2 __attribute__((ext_vector_type(2)));

__device__ __forceinline__ void mac2(unsigned w, unsigned r, float& acc){
#if __has_builtin(__builtin_amdgcn_fdot2)
  acc = __builtin_amdgcn_fdot2(__builtin_bit_cast(f16x2, w), __builtin_bit_cast(f16x2, r), acc, false);
#else
  union U { unsigned u; f16x2 v; } cw, cr;
  cw.u = w; cr.u = r;
  acc += (float)cw.v.x * (float)cr.v.x;
  acc += (float)cw.v.y * (float)cr.v.y;
#endif
}

__device__ __forceinline__ unsigned pack2(float a, float b){
  union { f16 h[2]; unsigned u; } cv;
  cv.h[0] = (f16)a; cv.h[1] = (f16)b;
  return cv.u;
}

__device__ __forceinline__ float wval(const float* __restrict__ Wrec,
    const float* __restrict__ Wm, const float* __restrict__ Ws,
    const float* __restrict__ Wf, int i, int j, int lo, int hi){
  if (j < lo || j >= hi) return 0.f;
  int idx = i*700 + j;
  return fmaxf(Wrec[idx], 0.f)*Wm[idx]*Ws[idx] + Wf[idx];
}

// ---------------- prep (identical to R13) ----------------
__global__ void prep_kernel(const float* __restrict__ Wrec, const float* __restrict__ Wm,
                            const float* __restrict__ Ws, const float* __restrict__ Wf,
                            const float* __restrict__ outw, uint4* __restrict__ Wp){
  int s = blockIdx.x*blockDim.x + threadIdx.x;
  if (s >= 13312) return;
  int G = s/26, j = s - G*26, q = j >> 1, rsel = j & 1;
  int mode = 0;               // 0 normal, 1 snr-c1 fused, 2 readout-ow
  int rowA = 0, pb = 0, lo = 0, hi = 0, sg = 0;
  if (G < 200){
    int g = G >> 2, c = G & 3;
    rowA = 2*g + rsel;
    pb = (c==0)?0:(c==1)?200:(c==2)?248:300;
    lo = (c==0)?0:(c==1)?400:(c==2)?500:600;
    hi = (c==0)?100:(c==1)?500:(c==2)?570:700;
  } else if (G < 300){
    int a = (G-200) >> 1, c = G & 1;
    rowA = 500 + 2*a + rsel;
    pb = c?248:200; lo = c?500:400; hi = c?600:500;
  } else if (G < 400){
    sg = (G-300) >> 1;
    if (!(G & 1)){ rowA = 300 + 2*sg + rsel; pb = 100; lo = 200; hi = 300; }  // snr<-stn
    else { mode = 1; pb = 0; }
  } else if (G < 450){
    int k = G-400; rowA = 200 + 2*k + rsel; pb = 48; lo = 100; hi = 200;      // stn<-gpe
  } else if (G < 500){
    int k = G-450; rowA = 400 + 2*k + rsel; pb = 148; lo = 300; hi = 400;     // thal<-snr
  } else {
    mode = 2; pb = 248;
  }
  unsigned pk[4];
  #pragma unroll
  for (int e = 0; e < 4; ++e){
    int p = pb + q*4 + e;
    float v0 = 0.f, v1 = 0.f;
    if (mode == 0){
      v0 = wval(Wrec,Wm,Ws,Wf, rowA, 2*p,   lo, hi);
      v1 = wval(Wrec,Wm,Ws,Wf, rowA, 2*p+1, lo, hi);
    } else if (mode == 1){
      int row = (p < 25) ? 300 + 2*sg + rsel : 100 + 2*sg + rsel;
      int l2  = (p < 25) ? 0 : 50, h2 = (p < 25) ? 50 : 100;
      v0 = wval(Wrec,Wm,Ws,Wf, row, 2*p,   l2, h2);
      v1 = wval(Wrec,Wm,Ws,Wf, row, 2*p+1, l2, h2);
    } else {
      if (rsel == 0 && p >= 250 && p < 300){
        int pp = p - 250;
        v0 = outw[2*pp]; v1 = outw[2*pp+1];
      }
    }
    pk[e] = pack2(v0, v1);
  }
  Wp[s] = make_uint4(pk[0], pk[1], pk[2], pk[3]);
}

// ---------------- main ----------------
__global__ __launch_bounds__(512)
void rnn_kernel(const float* __restrict__ inp, const float* __restrict__ noise,
                const uint4* __restrict__ Wp, float* __restrict__ out){
  __shared__ __align__(16) f16 rbuf[2][704];
  const int G = threadIdx.x;
  const int wid = G >> 6;
  const int b = blockIdx.x;

  // global r mirror: [buf(2)][batch(128)][352 u32], after the 13312 W quads
  unsigned* rgbase = (unsigned*)(Wp + 13312);
  unsigned* rg0 = rgbase + (size_t)b*352;            // buf 0
  unsigned* rg1 = rgbase + (size_t)(128 + b)*352;    // buf 1

  for (int k = G; k < 704; k += 512){ rbuf[0][k] = (f16)0.f; rbuf[1][k] = (f16)0.f; }
  for (int k = G; k < 352; k += 512){ rg0[k] = 0u; rg1[k] = 0u; }
  __syncthreads();   // drains vmcnt+lgkm: zeros visible

  const bool isStr = G < 200, isAlm = (G >= 200) && (G < 300),
             isSnr = (G >= 300) && (G < 400), isStn = (G >= 400) && (G < 450),
             isThal = (G >= 450) && (G < 500);
  const int c4 = G & 3, c2 = G & 1;
  const bool isIti = isStr && (c4 == 3);
  const bool isGpe = isSnr && (c2 == 1);
  const int g = G >> 2, a = (G-200) >> 1, sg = (G-300) >> 1;

  // r-read base (uint4 index = pair-base/4)
  const int rb = isStr ? ((c4==0)?0:(c4==1)?50:(c4==2)?62:75)
               : isAlm ? (c2?62:50)
               : isSnr ? (c2?0:25)
               : isStn ? 12 : isThal ? 37 : 62;

  bool own; int rowPair;
  if (isStr){ own = (c4==0)||(c4==3); rowPair = (c4==0) ? 2*g : 600+2*g; }
  else if (isAlm){ own = (c2==0); rowPair = 500+2*a; }
  else if (isSnr){ own = true; rowPair = c2 ? 100+2*sg : 300+2*sg; }
  else if (isStn){ own = true; rowPair = 200+2*(G-400); }
  else if (isThal){ own = true; rowPair = 400+2*(G-450); }
  else { own = false; rowPair = 0; }

  const bool comb1 = isStr || isAlm || isSnr;
  const bool comb4 = isStr;
  const float ton = (isSnr || isThal) ? 0.8f : (isStn ? 0.5f : 0.f);

  // resident W: 26 quads = 104 VGPR
  uint4 w[26];
  #pragma unroll
  for (int jj = 0; jj < 26; ++jj) w[jj] = Wp[G*26 + jj];

  // t=0 externals
  float2 nC = make_float2(0.f, 0.f), xC = make_float2(0.f, 0.f);
  if (own)  nC = *(const float2*)(noise + (size_t)b*700000 + rowPair);
  if (isIti) xC = *(const float2*)(inp + (size_t)b*100000 + (rowPair - 600));

  float h0 = 0.f, h1 = 0.f;

  for (int t = 0; t <= 1000; ++t){
    const f16* rc = rbuf[t & 1];
    f16* rn = rbuf[(t + 1) & 1];
    const uint4* rc4 = (const uint4*)rc;
    const unsigned long long* rgR =
        (const unsigned long long*)((t & 1) ? rg1 : rg0);
    unsigned* rgW = ((t + 1) & 1) ? rg1 : rg0;

    // next-step externals (~1300cy old by the vmcnt drain -> cheap)
    const int tn = (t < 999) ? t + 1 : 999;
    float2 nN = make_float2(0.f, 0.f), xN = make_float2(0.f, 0.f);
    if (own)  nN = *(const float2*)(noise + ((size_t)b*1000 + tn)*700 + rowPair);
    if (isIti) xN = *(const float2*)(inp + ((size_t)b*1000 + tn)*100 + (rowPair - 600));

    // ---- dot: 13 quads, 26 W quads, quad-6 element split ----
    // waves 0-4: LDS reads; waves 5-7: global mirror (VMEM pipe, L1-bypass)
    float aA1 = 0.f, aA2 = 0.f, aB1 = 0.f, aB2 = 0.f;
    #define MAC8(AC, BC, WA, WB) { \
      mac2(w[WA].x, r.x, AC); mac2(w[WA].y, r.y, AC); \
      mac2(w[WA].z, r.z, AC); mac2(w[WA].w, r.w, AC); \
      mac2(w[WB].x, r.x, BC); mac2(w[WB].y, r.y, BC); \
      mac2(w[WB].z, r.z, BC); mac2(w[WB].w, r.w, BC); }
    #define MACSPLIT() { \
      mac2(w[12].x, r.x, aA1); mac2(w[12].y, r.y, aA2); \
      mac2(w[12].z, r.z, aA2); mac2(w[12].w, r.w, aA2); \
      mac2(w[13].x, r.x, aB1); mac2(w[13].y, r.y, aB2); \
      mac2(w[13].z, r.z, aB2); mac2(w[13].w, r.w, aB2); }
    if (wid < 5){
      uint4 r;
      #define DOTL(Q, AC, BC) { r = rc4[rb + Q]; MAC8(AC, BC, 2*Q, 2*Q+1) }
      DOTL(0, aA1, aB1) DOTL(1, aA1, aB1) DOTL(2, aA1, aB1)
      DOTL(3, aA1, aB1) DOTL(4, aA1, aB1) DOTL(5, aA1, aB1)
      { r = rc4[rb + 6]; MACSPLIT() }
      DOTL(7, aA2, aB2) DOTL(8, aA2, aB2) DOTL(9, aA2, aB2)
      DOTL(10, aA2, aB2) DOTL(11, aA2, aB2) DOTL(12, aA2, aB2)
      #undef DOTL
    } else {
      const unsigned long long* p = rgR + 2*rb;
      uint4 r;
      #define GETQ(Q) { \
        unsigned long long lo_ = __hip_atomic_load(p + 2*Q,     __ATOMIC_RELAXED, __HIP_MEMORY_SCOPE_AGENT); \
        unsigned long long hi_ = __hip_atomic_load(p + 2*Q + 1, __ATOMIC_RELAXED, __HIP_MEMORY_SCOPE_AGENT); \
        r.x = (unsigned)lo_; r.y = (unsigned)(lo_ >> 32); \
        r.z = (unsigned)hi_; r.w = (unsigned)(hi_ >> 32); }
      #define DOTG(Q, AC, BC) { GETQ(Q) MAC8(AC, BC, 2*Q, 2*Q+1) }
      DOTG(0, aA1, aB1) DOTG(1, aA1, aB1) DOTG(2, aA1, aB1)
      DOTG(3, aA1, aB1) DOTG(4, aA1, aB1) DOTG(5, aA1, aB1)
      { GETQ(6) MACSPLIT() }
      DOTG(7, aA2, aB2) DOTG(8, aA2, aB2) DOTG(9, aA2, aB2)
      DOTG(10, aA2, aB2) DOTG(11, aA2, aB2) DOTG(12, aA2, aB2)
      #undef DOTG
      #undef GETQ
    }
    #undef MAC8
    #undef MACSPLIT

    // ---- in-wave combine ----
    const float sA = isGpe ? aA1 : (aA1 + aA2);
    const float sB = isGpe ? aB1 : (aB1 + aB2);
    const float rA = __shfl_xor(sA, 1), rB = __shfl_xor(sB, 1);
    float tA = comb1 ? (sA + rA) : sA;
    float tB = comb1 ? (sB + rB) : sB;
    const float uA = __shfl_xor(tA, 2), uB = __shfl_xor(tB, 2);
    if (comb4){ tA += uA; tB += uB; }

    // readout: lanes >= 500 computed ow-dot in tA
    if (G == 500 && t > 0) out[(size_t)b*1000 + (t - 1)] = tA;

    // ---- h update + r writes (LDS + mirror) ----
    if (own && t < 1000){
      const float d0 = isIti ? 0.f : (isGpe ? aA2 : tA);
      const float d1 = isIti ? 0.f : (isGpe ? aB2 : tB);
      const float e0 = isIti ? (xC.x + 0.01f*nC.x) : 0.f;
      const float e1 = isIti ? (xC.y + 0.01f*nC.y) : 0.f;
      h0 = h0 + 0.1f*(-h0 + d0 + ton + e0) + 0.01f*nC.x;
      h1 = h1 + 0.1f*(-h1 + d1 + ton + e1) + 0.01f*nC.y;
      const unsigned pv = pack2(fmaxf(h0, 0.f), fmaxf(h1, 0.f));
      ((unsigned*)rn)[rowPair >> 1] = pv;
      __hip_atomic_store(rgW + (rowPair >> 1), pv,
                         __ATOMIC_RELAXED, __HIP_MEMORY_SCOPE_AGENT);
    }
    nC = nN; xC = xN;

    // publish mirror + LDS before anyone reads: vmcnt(0) is cheap here
    // (only the 1-u32 store is young; prefetches are ~1300cy old)
    asm volatile("s_waitcnt vmcnt(0) lgkmcnt(0)" ::: "memory");
    __builtin_amdgcn_s_barrier();
  }
}

extern "C" void kernel_launch(void* const* d_in, const int* in_sizes, int n_in,
                              void* d_out, int out_size, void* d_ws, size_t ws_size,
                              hipStream_t stream){
  const float* inp   = (const float*)d_in[0];
  const float* noise = (const float*)d_in[1];
  const float* Wrec  = (const float*)d_in[2];
  const float* Wmask = (const float*)d_in[3];
  const float* Wsign = (const float*)d_in[4];
  const float* Wfix  = (const float*)d_in[5];
  const float* outw  = (const float*)d_in[7];
  float* out = (float*)d_out;
  uint4* Wp = (uint4*)d_ws;   // 13312 quads (213KB) + r mirror 2*128*352*4B (360KB)

  prep_kernel<<<52, 256, 0, stream>>>(Wrec, Wmask, Wsign, Wfix, outw, Wp);
  rnn_kernel<<<128, 512, 0, stream>>>(inp, noise, Wp, out);
}

// Round 15
// 829.765 us; speedup vs baseline: 4.3748x; 4.3748x over previous
//
#include <hip/hip_runtime.h>

// mRNN: h_{t+1} = h + 0.1*(-h + relu(h) @ W_eff^T + tonic + ext) + 0.01*noise
// out[b,t] = readout over relu(h[500:600]) via out_w
//
// R15 = R13 (844us, best) + ONE change: W replicated 8x in d_ws, each WG
// reads replica (blockIdx & 7) -> XCD-local copy under round-robin dispatch.
// Rationale: R13's VGPR_Count=76 proves the compiler REMATERIALIZED the 26
// "resident" W quads into per-step L2 loads; all 128 WGs stream the SAME
// 213KB of addresses -> same-line L2-slice contention. Replication gives
// each XCD a private copy. (R14 lesson: global r-mirror + per-step vmcnt(0)
// publish = 220MB HBM writes, 4x regression. Reverted.)

typedef _Float16 f16;
typedef _Float16 f16x2 __attribute__((ext_vector_type(2)));

__device__ __forceinline__ void mac2(unsigned w, unsigned r, float& acc){
#if __has_builtin(__builtin_amdgcn_fdot2)
  acc = __builtin_amdgcn_fdot2(__builtin_bit_cast(f16x2, w), __builtin_bit_cast(f16x2, r), acc, false);
#else
  union U { unsigned u; f16x2 v; } cw, cr;
  cw.u = w; cr.u = r;
  acc += (float)cw.v.x * (float)cr.v.x;
  acc += (float)cw.v.y * (float)cr.v.y;
#endif
}

__device__ __forceinline__ unsigned pack2(float a, float b){
  union { f16 h[2]; unsigned u; } cv;
  cv.h[0] = (f16)a; cv.h[1] = (f16)b;
  return cv.u;
}

__device__ __forceinline__ void wait_lgkm0(){
  asm volatile("s_waitcnt lgkmcnt(0)" ::: "memory");
}

__device__ __forceinline__ float wval(const float* __restrict__ Wrec,
    const float* __restrict__ Wm, const float* __restrict__ Ws,
    const float* __restrict__ Wf, int i, int j, int lo, int hi){
  if (j < lo || j >= hi) return 0.f;
  int idx = i*700 + j;
  return fmaxf(Wrec[idx], 0.f)*Wm[idx]*Ws[idx] + Wf[idx];
}

// ---------------- prep (identical to R13; writes replica 0) ----------------
__global__ void prep_kernel(const float* __restrict__ Wrec, const float* __restrict__ Wm,
                            const float* __restrict__ Ws, const float* __restrict__ Wf,
                            const float* __restrict__ outw, uint4* __restrict__ Wp){
  int s = blockIdx.x*blockDim.x + threadIdx.x;
  if (s >= 13312) return;
  int G = s/26, j = s - G*26, q = j >> 1, rsel = j & 1;
  int mode = 0;               // 0 normal, 1 snr-c1 fused, 2 readout-ow
  int rowA = 0, pb = 0, lo = 0, hi = 0, sg = 0;
  if (G < 200){
    int g = G >> 2, c = G & 3;
    rowA = 2*g + rsel;
    pb = (c==0)?0:(c==1)?200:(c==2)?248:300;
    lo = (c==0)?0:(c==1)?400:(c==2)?500:600;
    hi = (c==0)?100:(c==1)?500:(c==2)?570:700;
  } else if (G < 300){
    int a = (G-200) >> 1, c = G & 1;
    rowA = 500 + 2*a + rsel;
    pb = c?248:200; lo = c?500:400; hi = c?600:500;
  } else if (G < 400){
    sg = (G-300) >> 1;
    if (!(G & 1)){ rowA = 300 + 2*sg + rsel; pb = 100; lo = 200; hi = 300; }  // snr<-stn
    else { mode = 1; pb = 0; }
  } else if (G < 450){
    int k = G-400; rowA = 200 + 2*k + rsel; pb = 48; lo = 100; hi = 200;      // stn<-gpe
  } else if (G < 500){
    int k = G-450; rowA = 400 + 2*k + rsel; pb = 148; lo = 300; hi = 400;     // thal<-snr
  } else {
    mode = 2; pb = 248;
  }
  unsigned pk[4];
  #pragma unroll
  for (int e = 0; e < 4; ++e){
    int p = pb + q*4 + e;
    float v0 = 0.f, v1 = 0.f;
    if (mode == 0){
      v0 = wval(Wrec,Wm,Ws,Wf, rowA, 2*p,   lo, hi);
      v1 = wval(Wrec,Wm,Ws,Wf, rowA, 2*p+1, lo, hi);
    } else if (mode == 1){
      int row = (p < 25) ? 300 + 2*sg + rsel : 100 + 2*sg + rsel;
      int l2  = (p < 25) ? 0 : 50, h2 = (p < 25) ? 50 : 100;
      v0 = wval(Wrec,Wm,Ws,Wf, row, 2*p,   l2, h2);
      v1 = wval(Wrec,Wm,Ws,Wf, row, 2*p+1, l2, h2);
    } else {
      if (rsel == 0 && p >= 250 && p < 300){
        int pp = p - 250;
        v0 = outw[2*pp]; v1 = outw[2*pp+1];
      }
    }
    pk[e] = pack2(v0, v1);
  }
  Wp[s] = make_uint4(pk[0], pk[1], pk[2], pk[3]);
}

// replicate replica 0 into replicas 1..nrep-1
__global__ void replicate_kernel(uint4* __restrict__ Wp, int nrep){
  int s = blockIdx.x*blockDim.x + threadIdx.x;
  int total = 13312*(nrep-1);
  if (s >= total) return;
  int r = s / 13312 + 1, q = s % 13312;
  Wp[(size_t)r*13312 + q] = Wp[q];
}

// ---------------- main ----------------
__global__ __launch_bounds__(512)
void rnn_kernel(const float* __restrict__ inp, const float* __restrict__ noise,
                const uint4* __restrict__ Wp, float* __restrict__ out,
                int repMask){
  __shared__ __align__(16) f16 rbuf[2][704];
  const int G = threadIdx.x;
  const int b = blockIdx.x;
  // XCD-local replica (blockIdx -> XCD is round-robin on MI355X)
  const uint4* __restrict__ WpX = Wp + (size_t)13312 * (b & repMask);

  for (int k = G; k < 704; k += 512){ rbuf[0][k] = (f16)0.f; rbuf[1][k] = (f16)0.f; }
  __syncthreads();

  const bool isStr = G < 200, isAlm = (G >= 200) && (G < 300),
             isSnr = (G >= 300) && (G < 400), isStn = (G >= 400) && (G < 450),
             isThal = (G >= 450) && (G < 500);
  const int c4 = G & 3, c2 = G & 1;
  const bool isIti = isStr && (c4 == 3);
  const bool isGpe = isSnr && (c2 == 1);
  const int g = G >> 2, a = (G-200) >> 1, sg = (G-300) >> 1;

  // r-read base (uint4 index = pair-base/4)
  const int rb = isStr ? ((c4==0)?0:(c4==1)?50:(c4==2)?62:75)
               : isAlm ? (c2?62:50)
               : isSnr ? (c2?0:25)
               : isStn ? 12 : isThal ? 37 : 62;

  bool own; int rowPair;
  if (isStr){ own = (c4==0)||(c4==3); rowPair = (c4==0) ? 2*g : 600+2*g; }
  else if (isAlm){ own = (c2==0); rowPair = 500+2*a; }
  else if (isSnr){ own = true; rowPair = c2 ? 100+2*sg : 300+2*sg; }
  else if (isStn){ own = true; rowPair = 200+2*(G-400); }
  else if (isThal){ own = true; rowPair = 400+2*(G-450); }
  else { own = false; rowPair = 0; }

  const bool comb1 = isStr || isAlm || isSnr;
  const bool comb4 = isStr;
  const float ton = (isSnr || isThal) ? 0.8f : (isStn ? 0.5f : 0.f);

  // W working set (compiler remats these as per-step L2 loads; replica-local)
  uint4 w[26];
  #pragma unroll
  for (int jj = 0; jj < 26; ++jj) w[jj] = WpX[G*26 + jj];

  // t=0 externals
  float2 nC = make_float2(0.f, 0.f), xC = make_float2(0.f, 0.f);
  if (own)  nC = *(const float2*)(noise + (size_t)b*700000 + rowPair);
  if (isIti) xC = *(const float2*)(inp + (size_t)b*100000 + (rowPair - 600));

  float h0 = 0.f, h1 = 0.f;

  for (int t = 0; t <= 1000; ++t){
    const f16* rc = rbuf[t & 1];
    f16* rn = rbuf[(t + 1) & 1];
    const uint4* rc4 = (const uint4*)rc;

    // next-step externals (ride across the raw barrier) [R10-proven]
    const int tn = (t < 999) ? t + 1 : 999;
    float2 nN = make_float2(0.f, 0.f), xN = make_float2(0.f, 0.f);
    if (own)  nN = *(const float2*)(noise + ((size_t)b*1000 + tn)*700 + rowPair);
    if (isIti) xN = *(const float2*)(inp + ((size_t)b*1000 + tn)*100 + (rowPair - 600));

    // ---- uniform dot: 13 reads, 26 W quads, quad-6 element split ----
    float aA1 = 0.f, aA2 = 0.f, aB1 = 0.f, aB2 = 0.f;
    {
      uint4 r;
      #define DOTQ(Q, AC, BC) { r = rc4[rb + Q]; \
        mac2(w[2*Q].x, r.x, AC); mac2(w[2*Q].y, r.y, AC); \
        mac2(w[2*Q].z, r.z, AC); mac2(w[2*Q].w, r.w, AC); \
        mac2(w[2*Q+1].x, r.x, BC); mac2(w[2*Q+1].y, r.y, BC); \
        mac2(w[2*Q+1].z, r.z, BC); mac2(w[2*Q+1].w, r.w, BC); }
      DOTQ(0, aA1, aB1) DOTQ(1, aA1, aB1) DOTQ(2, aA1, aB1)
      DOTQ(3, aA1, aB1) DOTQ(4, aA1, aB1) DOTQ(5, aA1, aB1)
      { r = rc4[rb + 6];
        mac2(w[12].x, r.x, aA1); mac2(w[12].y, r.y, aA2);
        mac2(w[12].z, r.z, aA2); mac2(w[12].w, r.w, aA2);
        mac2(w[13].x, r.x, aB1); mac2(w[13].y, r.y, aB2);
        mac2(w[13].z, r.z, aB2); mac2(w[13].w, r.w, aB2); }
      DOTQ(7, aA2, aB2) DOTQ(8, aA2, aB2) DOTQ(9, aA2, aB2)
      DOTQ(10, aA2, aB2) DOTQ(11, aA2, aB2) DOTQ(12, aA2, aB2)
      #undef DOTQ
    }

    // ---- in-wave combine ----
    const float sA = isGpe ? aA1 : (aA1 + aA2);
    const float sB = isGpe ? aB1 : (aB1 + aB2);
    const float rA = __shfl_xor(sA, 1), rB = __shfl_xor(sB, 1);
    float tA = comb1 ? (sA + rA) : sA;
    float tB = comb1 ? (sB + rB) : sB;
    const float uA = __shfl_xor(tA, 2), uB = __shfl_xor(tB, 2);
    if (comb4){ tA += uA; tB += uB; }

    // readout: lanes >= 500 computed ow-dot in tA
    if (G == 500 && t > 0) out[(size_t)b*1000 + (t - 1)] = tA;

    // ---- h update + packed r-write (owners only) ----
    if (own && t < 1000){
      const float d0 = isIti ? 0.f : (isGpe ? aA2 : tA);
      const float d1 = isIti ? 0.f : (isGpe ? aB2 : tB);
      const float e0 = isIti ? (xC.x + 0.01f*nC.x) : 0.f;
      const float e1 = isIti ? (xC.y + 0.01f*nC.y) : 0.f;
      h0 = h0 + 0.1f*(-h0 + d0 + ton + e0) + 0.01f*nC.x;
      h1 = h1 + 0.1f*(-h1 + d1 + ton + e1) + 0.01f*nC.y;
      ((unsigned*)rn)[rowPair >> 1] = pack2(fmaxf(h0, 0.f), fmaxf(h1, 0.f));
    }
    nC = nN; xC = xN;

    wait_lgkm0();                      // own ds ops retired; NO vmcnt drain
    __builtin_amdgcn_s_barrier();      // one barrier per step
  }
}

extern "C" void kernel_launch(void* const* d_in, const int* in_sizes, int n_in,
                              void* d_out, int out_size, void* d_ws, size_t ws_size,
                              hipStream_t stream){
  const float* inp   = (const float*)d_in[0];
  const float* noise = (const float*)d_in[1];
  const float* Wrec  = (const float*)d_in[2];
  const float* Wmask = (const float*)d_in[3];
  const float* Wsign = (const float*)d_in[4];
  const float* Wfix  = (const float*)d_in[5];
  const float* outw  = (const float*)d_in[7];
  float* out = (float*)d_out;
  uint4* Wp = (uint4*)d_ws;

  // replicas: power-of-two count that fits ws (8 x 13312 x 16B = 1.7MB ideal)
  size_t cap = ws_size / 16;
  int nrep = 1;
  while (nrep < 8 && (size_t)(nrep*2)*13312 <= cap) nrep *= 2;

  prep_kernel<<<52, 256, 0, stream>>>(Wrec, Wmask, Wsign, Wfix, outw, Wp);
  if (nrep > 1){
    int total = 13312*(nrep-1);
    replicate_kernel<<<(total + 255)/256, 256, 0, stream>>>(Wp, nrep);
  }
  rnn_kernel<<<128, 512, 0, stream>>>(inp, noise, Wp, out, nrep - 1);
}